// Round 4
// baseline (532.740 us; speedup 1.0000x reference)
//
#include <hip/hip_runtime.h>
#include <hip/hip_bf16.h>

#define HEADS 8
#define NTOK 64
#define DIM 256

typedef __attribute__((ext_vector_type(8))) short bf16x8;
typedef __attribute__((ext_vector_type(4))) short bf16x4;
typedef __attribute__((ext_vector_type(4))) float f32x4;
typedef unsigned short u16;

__device__ __forceinline__ u16 f2bf(float f) {
    union { float f; unsigned u; } c; c.f = f;
    unsigned u = c.u;
    unsigned rounded = u + 0x7FFF + ((u >> 16) & 1);
    return (u16)(rounded >> 16);
}

__device__ __forceinline__ float dpp_xor1(float x) {
    return __int_as_float(__builtin_amdgcn_mov_dpp(__float_as_int(x), 0xB1, 0xF, 0xF, true));
}
__device__ __forceinline__ float dpp_xor2(float x) {
    return __int_as_float(__builtin_amdgcn_mov_dpp(__float_as_int(x), 0x4E, 0xF, 0xF, true));
}

// ---------------- prep: weights fp32->bf16, fused bias table ----------------
__global__ void prep_kernel(const float* __restrict__ wqkv,
                            const float* __restrict__ wproj,
                            const float* __restrict__ table,
                            const int* __restrict__ rel_index,
                            const float* __restrict__ mask,
                            u16* __restrict__ wq_bf,
                            u16* __restrict__ wp_bf,
                            float* __restrict__ bias) {
    const int NQ = 768 * 256;
    const int NP = 256 * 256;
    const int NB = HEADS * NTOK * NTOK;
    int total = NQ + NP + NB;
    for (int i = blockIdx.x * blockDim.x + threadIdx.x; i < total;
         i += gridDim.x * blockDim.x) {
        if (i < NQ) {
            wq_bf[i] = f2bf(wqkv[i]);
        } else if (i < NQ + NP) {
            wp_bf[i - NQ] = f2bf(wproj[i - NQ]);
        } else {
            int j = i - (NQ + NP);          // j = h*4096 + n*64 + m
            int h = j >> 12;
            int nm = j & 4095;
            bias[j] = table[rel_index[nm] * HEADS + h] + mask[j];
        }
    }
}

// ---------------- fused window attention ----------------
// 512 threads (8 waves), 1 window/block. Wave w owns head w end-to-end:
// QKV (Q,K register-resident) -> S via 16x16x16 MFMA on the raw accumulators
// -> softmax -> PV -> O. Barrier-free between x-stage and proj.
__launch_bounds__(512, 2)
__global__ void win_attn_kernel(const float* __restrict__ x,
                                const u16* __restrict__ wq_bf,
                                const u16* __restrict__ wp_bf,
                                const float* __restrict__ bias,
                                const float* __restrict__ b_proj,
                                float* __restrict__ out) {
    __shared__ u16 smem[60928];          // 121,856 B
    u16* s_x  = smem;                    // [64][264] x bf16
    u16* s_vt = smem + 16896;            // [256][72] V^T [h*32+d][token]
    u16* s_o  = smem + 35328;            // [64][264] attention output O
    u16* s_p  = smem + 52224;            // 8 x [16][68] per-wave P staging

    const int b = blockIdx.x;
    const int tid = threadIdx.x;
    const int w = tid >> 6;      // wave 0..7 == head
    const int l = tid & 63;
    const int l16 = l & 15;
    const int lhi = l >> 4;

    // ---- Phase 0: load x window -> bf16 LDS ----
    const float* xw = x + (size_t)b * (NTOK * DIM);
#pragma unroll
    for (int it = 0; it < 8; ++it) {
        int idx4 = tid + it * 512;                 // float4 index 0..4095
        float4 v = reinterpret_cast<const float4*>(xw)[idx4];
        int row = idx4 >> 6;
        int col = (idx4 & 63) * 4;
        ushort4 o;
        o.x = f2bf(v.x); o.y = f2bf(v.y); o.z = f2bf(v.z); o.w = f2bf(v.w);
        *reinterpret_cast<ushort4*>(&s_x[row * 264 + col]) = o;
    }
    __syncthreads();

    const int h = w;
    // ---- Phase 1: per-head QKV GEMM ----
    // Q,K swapped: D[col][token] (lane l16=token, col=lhi*4+r)
    // V normal:    D[token][col] (lane l16=col,   token=lhi*4+r)
    f32x4 qacc[2][4], kacc[2][4], vacc[4][2];
    const f32x4 zero = {0.f, 0.f, 0.f, 0.f};
#pragma unroll
    for (int ct = 0; ct < 2; ++ct)
#pragma unroll
        for (int tt = 0; tt < 4; ++tt) {
            qacc[ct][tt] = zero; kacc[ct][tt] = zero; vacc[tt][ct] = zero;
        }

    const u16* rq0 = wq_bf + (h * 32 + l16) * 256;
    const u16* rq1 = rq0 + 16 * 256;
    const u16* rk0 = wq_bf + (256 + h * 32 + l16) * 256;
    const u16* rk1 = rk0 + 16 * 256;
    const u16* rv0 = wq_bf + (512 + h * 32 + l16) * 256;
    const u16* rv1 = rv0 + 16 * 256;

    bf16x8 wq0 = *reinterpret_cast<const bf16x8*>(rq0 + lhi * 8);
    bf16x8 wq1 = *reinterpret_cast<const bf16x8*>(rq1 + lhi * 8);
    bf16x8 wk0 = *reinterpret_cast<const bf16x8*>(rk0 + lhi * 8);
    bf16x8 wk1 = *reinterpret_cast<const bf16x8*>(rk1 + lhi * 8);
    bf16x8 wv0 = *reinterpret_cast<const bf16x8*>(rv0 + lhi * 8);
    bf16x8 wv1 = *reinterpret_cast<const bf16x8*>(rv1 + lhi * 8);

    for (int ks = 0; ks < 8; ++ks) {
        const int k0 = ks * 32 + lhi * 8;
        bf16x8 xf[4];
#pragma unroll
        for (int tt = 0; tt < 4; ++tt)
            xf[tt] = *reinterpret_cast<const bf16x8*>(&s_x[(tt * 16 + l16) * 264 + k0]);
        bf16x8 nq0, nq1, nk0, nk1, nv0, nv1;
        if (ks < 7) {
            nq0 = *reinterpret_cast<const bf16x8*>(rq0 + k0 + 32);
            nq1 = *reinterpret_cast<const bf16x8*>(rq1 + k0 + 32);
            nk0 = *reinterpret_cast<const bf16x8*>(rk0 + k0 + 32);
            nk1 = *reinterpret_cast<const bf16x8*>(rk1 + k0 + 32);
            nv0 = *reinterpret_cast<const bf16x8*>(rv0 + k0 + 32);
            nv1 = *reinterpret_cast<const bf16x8*>(rv1 + k0 + 32);
        }
#pragma unroll
        for (int tt = 0; tt < 4; ++tt) {
            qacc[0][tt] = __builtin_amdgcn_mfma_f32_16x16x32_bf16(wq0, xf[tt], qacc[0][tt], 0, 0, 0);
            qacc[1][tt] = __builtin_amdgcn_mfma_f32_16x16x32_bf16(wq1, xf[tt], qacc[1][tt], 0, 0, 0);
            kacc[0][tt] = __builtin_amdgcn_mfma_f32_16x16x32_bf16(wk0, xf[tt], kacc[0][tt], 0, 0, 0);
            kacc[1][tt] = __builtin_amdgcn_mfma_f32_16x16x32_bf16(wk1, xf[tt], kacc[1][tt], 0, 0, 0);
            vacc[tt][0] = __builtin_amdgcn_mfma_f32_16x16x32_bf16(xf[tt], wv0, vacc[tt][0], 0, 0, 0);
            vacc[tt][1] = __builtin_amdgcn_mfma_f32_16x16x32_bf16(xf[tt], wv1, vacc[tt][1], 0, 0, 0);
        }
        wq0 = nq0; wq1 = nq1; wk0 = nk0; wk1 = nk1; wv0 = nv0; wv1 = nv1;
    }

    // Pack Q,K accumulators -> 16x16x16 A/B fragments (layout identity!)
    bf16x4 qf[4][2], kf[4][2];
#pragma unroll
    for (int tt = 0; tt < 4; ++tt)
#pragma unroll
        for (int ct = 0; ct < 2; ++ct) {
            bf16x4 q, k;
#pragma unroll
            for (int r = 0; r < 4; ++r) {
                q[r] = (short)f2bf(qacc[ct][tt][r]);
                k[r] = (short)f2bf(kacc[ct][tt][r]);
            }
            qf[tt][ct] = q; kf[tt][ct] = k;
        }
    // V -> LDS (packed ushort4 writes), V^T[vcol][token]
#pragma unroll
    for (int tt = 0; tt < 4; ++tt)
#pragma unroll
        for (int ct = 0; ct < 2; ++ct) {
            ushort4 o;
            o.x = f2bf(vacc[tt][ct][0]); o.y = f2bf(vacc[tt][ct][1]);
            o.z = f2bf(vacc[tt][ct][2]); o.w = f2bf(vacc[tt][ct][3]);
            *reinterpret_cast<ushort4*>(
                &s_vt[(h * 32 + ct * 16 + l16) * 72 + tt * 16 + lhi * 4]) = o;
        }

    // ---- Phase 2: attention (wave-local, no barrier) ----
    {
        bf16x8 vfrag[2][2];
#pragma unroll
        for (int dt = 0; dt < 2; ++dt)
#pragma unroll
            for (int kv = 0; kv < 2; ++kv)
                vfrag[dt][kv] = *reinterpret_cast<const bf16x8*>(
                    &s_vt[(h * 32 + dt * 16 + l16) * 72 + kv * 32 + lhi * 8]);

        u16* Pw = s_p + w * 1088;      // [16][68] unnormalized P
        const float scale = 0.17677669529663687f;
        const float* biash = bias + h * 4096;

#pragma unroll
        for (int nt = 0; nt < 4; ++nt) {
            f32x4 sacc[4];
#pragma unroll
            for (int mt = 0; mt < 4; ++mt) {
                sacc[mt] = __builtin_amdgcn_mfma_f32_16x16x16bf16_1k(qf[nt][0], kf[mt][0], zero, 0, 0, 0);
                sacc[mt] = __builtin_amdgcn_mfma_f32_16x16x16bf16_1k(qf[nt][1], kf[mt][1], sacc[mt], 0, 0, 0);
            }
            float inv_[4];
#pragma unroll
            for (int r = 0; r < 4; ++r) {
                int row = nt * 16 + lhi * 4 + r;
                float p[4];
                float sum = 0.f;
#pragma unroll
                for (int mt = 0; mt < 4; ++mt) {
                    // scores bounded -> exp without max-subtract
                    p[mt] = __expf(sacc[mt][r] * scale + biash[row * 64 + mt * 16 + l16]);
                    sum += p[mt];
                }
                sum += dpp_xor1(sum);
                sum += dpp_xor2(sum);
                sum += __shfl_xor(sum, 4, 64);
                sum += __shfl_xor(sum, 8, 64);
                inv_[r] = 1.0f / sum;
#pragma unroll
                for (int mt = 0; mt < 4; ++mt)
                    Pw[(lhi * 4 + r) * 68 + mt * 16 + l16] = f2bf(p[mt]);
            }
            // PV (wave-internal LDS RAW, in-order pipe)
            bf16x8 pa0 = *reinterpret_cast<const bf16x8*>(&Pw[l16 * 68 + lhi * 8]);
            bf16x8 pa1 = *reinterpret_cast<const bf16x8*>(&Pw[l16 * 68 + 32 + lhi * 8]);
            f32x4 oacc[2];
#pragma unroll
            for (int dt = 0; dt < 2; ++dt) {
                oacc[dt] = __builtin_amdgcn_mfma_f32_16x16x32_bf16(pa0, vfrag[dt][0], zero, 0, 0, 0);
                oacc[dt] = __builtin_amdgcn_mfma_f32_16x16x32_bf16(pa1, vfrag[dt][1], oacc[dt], 0, 0, 0);
            }
#pragma unroll
            for (int dt = 0; dt < 2; ++dt)
#pragma unroll
                for (int r = 0; r < 4; ++r) {
                    int row = nt * 16 + lhi * 4 + r;
                    s_o[row * 264 + h * 32 + dt * 16 + l16] = f2bf(oacc[dt][r] * inv_[r]);
                }
        }
    }
    __syncthreads();

    // ---- Phase 3: proj GEMM (swapped): D[projcol][token]; 2 tiles/wave ----
    f32x4 acc3[2][4];
#pragma unroll
    for (int t = 0; t < 2; ++t)
#pragma unroll
        for (int tt = 0; tt < 4; ++tt) acc3[t][tt] = zero;

    const u16* prow0 = wp_bf + (w * 16 + l16) * 256;
    const u16* prow1 = wp_bf + ((w + 8) * 16 + l16) * 256;
    bf16x8 wp0 = *reinterpret_cast<const bf16x8*>(prow0 + lhi * 8);
    bf16x8 wp1 = *reinterpret_cast<const bf16x8*>(prow1 + lhi * 8);
    for (int ks = 0; ks < 8; ++ks) {
        const int k0 = ks * 32 + lhi * 8;
        bf16x8 np0, np1;
        if (ks < 7) {
            np0 = *reinterpret_cast<const bf16x8*>(prow0 + k0 + 32);
            np1 = *reinterpret_cast<const bf16x8*>(prow1 + k0 + 32);
        }
#pragma unroll
        for (int tt = 0; tt < 4; ++tt) {
            bf16x8 of = *reinterpret_cast<const bf16x8*>(&s_o[(tt * 16 + l16) * 264 + k0]);
            acc3[0][tt] = __builtin_amdgcn_mfma_f32_16x16x32_bf16(wp0, of, acc3[0][tt], 0, 0, 0);
            acc3[1][tt] = __builtin_amdgcn_mfma_f32_16x16x32_bf16(wp1, of, acc3[1][tt], 0, 0, 0);
        }
        wp0 = np0; wp1 = np1;
    }
    float* outw = out + (size_t)b * (NTOK * DIM);
#pragma unroll
    for (int t = 0; t < 2; ++t) {
        int colb = (w + t * 8) * 16 + lhi * 4;
        float4 bp = *reinterpret_cast<const float4*>(&b_proj[colb]);
#pragma unroll
        for (int tt = 0; tt < 4; ++tt) {
            float4 o;
            o.x = acc3[t][tt][0] + bp.x;
            o.y = acc3[t][tt][1] + bp.y;
            o.z = acc3[t][tt][2] + bp.z;
            o.w = acc3[t][tt][3] + bp.w;
            *reinterpret_cast<float4*>(&outw[(tt * 16 + l16) * 256 + colb]) = o;
        }
    }
}

extern "C" void kernel_launch(void* const* d_in, const int* in_sizes, int n_in,
                              void* d_out, int out_size, void* d_ws, size_t ws_size,
                              hipStream_t stream) {
    const float* x     = (const float*)d_in[0];
    const float* mask  = (const float*)d_in[1];
    const float* wqkv  = (const float*)d_in[2];
    const float* wproj = (const float*)d_in[3];
    const float* bproj = (const float*)d_in[4];
    const float* table = (const float*)d_in[5];
    const int*   relix = (const int*)d_in[6];

    u16*   wq_bf = (u16*)d_ws;                 // 768*256 bf16
    u16*   wp_bf = wq_bf + 768 * 256;          // 256*256 bf16
    float* bias  = (float*)(wp_bf + 256 * 256); // 8*64*64 fp32

    prep_kernel<<<64, 512, 0, stream>>>(wqkv, wproj, table, relix, mask,
                                        wq_bf, wp_bf, bias);
    win_attn_kernel<<<4096, 512, 0, stream>>>(x, wq_bf, wp_bf, bias, bproj,
                                              (float*)d_out);
}